// Round 4
// baseline (344.238 us; speedup 1.0000x reference)
//
#include <hip/hip_runtime.h>

#define TDIM 8192
#define NB 8
#define CD 512
#define SCALE 0.125f

typedef unsigned int u32;
typedef unsigned short u16;
typedef __bf16 bf16;
typedef bf16 bf16x8 __attribute__((ext_vector_type(8)));
typedef float f32x4 __attribute__((ext_vector_type(4)));
typedef u16 u16x4 __attribute__((ext_vector_type(4)));
typedef u16 u16x8 __attribute__((ext_vector_type(8)));

__device__ __forceinline__ u16 f2bf(float f) {
  u32 u = __float_as_uint(f);
  return (u16)((u + 0x7FFFu + ((u >> 16) & 1u)) >> 16);
}

__device__ __forceinline__ void gload16(const void* g, void* l) {
  __builtin_amdgcn_global_load_lds((const __attribute__((address_space(1))) u32*)g,
                                   (__attribute__((address_space(3))) u32*)l, 16, 0, 0);
}

// ---------------- K0: transpose + cast q: [b][c][t] f32 -> qT [b][t][c] bf16 ----------------
__global__ __launch_bounds__(256) void k_tq(const float* __restrict__ q, u16* __restrict__ qT) {
  __shared__ float tile[64][65];
  const int b = blockIdx.z, cb = blockIdx.y * 64, tb = blockIdx.x * 64;
  const int tid = threadIdx.x, r = tid >> 2, qd = tid & 3;
  const float* src = q + ((size_t)(b * CD + cb + r)) * TDIM + tb;
#pragma unroll
  for (int j = 0; j < 4; ++j) {
    const float4 v = *(const float4*)(src + j * 16 + qd * 4);
    tile[r][j * 16 + qd * 4 + 0] = v.x;
    tile[r][j * 16 + qd * 4 + 1] = v.y;
    tile[r][j * 16 + qd * 4 + 2] = v.z;
    tile[r][j * 16 + qd * 4 + 3] = v.w;
  }
  __syncthreads();
  u16x8 o0, o1;
#pragma unroll
  for (int i = 0; i < 8; ++i) o0[i] = f2bf(tile[qd * 16 + i][r]);
#pragma unroll
  for (int i = 0; i < 8; ++i) o1[i] = f2bf(tile[qd * 16 + 8 + i][r]);
  u16* dst = qT + ((size_t)b * TDIM + tb + r) * CD + cb + qd * 16;
  *(u16x8*)dst = o0;
  *(u16x8*)(dst + 8) = o1;
}

// ---------------- cast weights: Wq (512x512) ++ Wkv (1024x512) -> Wall bf16 ----------------
__global__ __launch_bounds__(256) void k_cast_w(const float* __restrict__ Wq, const float* __restrict__ Wkv,
                                                u16* __restrict__ Wall) {
  const int idx = (blockIdx.x * 256 + threadIdx.x) * 4;
  float4 v;
  if (idx < 512 * 512) v = *(const float4*)(Wq + idx);
  else                 v = *(const float4*)(Wkv + (idx - 512 * 512));
  u16x4 p;
  p[0] = f2bf(v.x); p[1] = f2bf(v.y); p[2] = f2bf(v.z); p[3] = f2bf(v.w);
  *(u16x4*)(Wall + idx) = p;
}

// ============ 256x256 GEMM core (m201 geometry): BK=64, 8 waves 2Mx4N (wave=128x64, acc[8][4]),
// LDS dbuf 2x64KB, 4 quadrant-phases/K-tile, stage(kt+1) at kt-ph0, vmcnt(0) once per K-tile. ============
__device__ __forceinline__ void stageAB(const u16* __restrict__ A, const u16* __restrict__ B,
                                        char* buf, int w, int rr, int ch, int kt) {
#pragma unroll
  for (int i = 0; i < 4; ++i) {
    const int row = w * 32 + i * 8 + rr;           // row&7 == rr
    const size_t go = (size_t)row * CD + kt * 64 + ((ch ^ rr) << 3);
    gload16(A + go, buf + (w * 4 + i) * 1024);
    gload16(B + go, buf + 32768 + (w * 4 + i) * 1024);
  }
}

__device__ __forceinline__ void gemm256(const u16* __restrict__ A, const u16* __restrict__ B,
                                        char* lds, f32x4 (&acc)[8][4]) {
  const int tid = threadIdx.x, lane = tid & 63, w = tid >> 6;
  const int wr = w >> 2, wc = w & 3;
  const int rr = lane >> 3, ch = lane & 7;
  const int lo16 = lane & 15, hi4 = lane >> 4;
  stageAB(A, B, lds, w, rr, ch, 0);
  stageAB(A, B, lds + 65536, w, rr, ch, 1);
  asm volatile("s_waitcnt vmcnt(8)" ::: "memory");   // kt0 landed; kt1's 8 in flight
  __builtin_amdgcn_s_barrier();
#pragma unroll 1
  for (int kt = 0; kt < 8; ++kt) {
    char* bc = lds + (kt & 1) * 65536;
    bf16x8 av[4], bv[4];
    // ---- phase 0: ks=0, am 0..3, load bv(ks0); issue stage(kt+1) into kt-1's (free) buffer
#pragma unroll
    for (int i = 0; i < 4; ++i) {
      const int rowA = wr * 128 + i * 16 + lo16;
      av[i] = *(const bf16x8*)(bc + rowA * 128 + ((hi4 * 16) ^ ((rowA & 7) << 4)));
      const int rowB = wc * 64 + i * 16 + lo16;
      bv[i] = *(const bf16x8*)(bc + 32768 + rowB * 128 + ((hi4 * 16) ^ ((rowB & 7) << 4)));
    }
    if (kt >= 1 && kt <= 6)
      stageAB(A, B, lds + ((kt + 1) & 1) * 65536, w, rr, ch, kt + 1);
    __builtin_amdgcn_s_barrier();
    asm volatile("s_waitcnt lgkmcnt(0)" ::: "memory");
    __builtin_amdgcn_sched_barrier(0);
    __builtin_amdgcn_s_setprio(1);
#pragma unroll
    for (int m = 0; m < 4; ++m)
#pragma unroll
      for (int n = 0; n < 4; ++n)
        acc[m][n] = __builtin_amdgcn_mfma_f32_16x16x32_bf16(av[m], bv[n], acc[m][n], 0, 0, 0);
    __builtin_amdgcn_s_setprio(0);
    __builtin_amdgcn_s_barrier();
    // ---- phase 1: ks=0, am 4..7 (reuse bv)
#pragma unroll
    for (int i = 0; i < 4; ++i) {
      const int rowA = wr * 128 + (4 + i) * 16 + lo16;
      av[i] = *(const bf16x8*)(bc + rowA * 128 + ((hi4 * 16) ^ ((rowA & 7) << 4)));
    }
    __builtin_amdgcn_s_barrier();
    asm volatile("s_waitcnt lgkmcnt(0)" ::: "memory");
    __builtin_amdgcn_sched_barrier(0);
    __builtin_amdgcn_s_setprio(1);
#pragma unroll
    for (int m = 0; m < 4; ++m)
#pragma unroll
      for (int n = 0; n < 4; ++n)
        acc[4 + m][n] = __builtin_amdgcn_mfma_f32_16x16x32_bf16(av[m], bv[n], acc[4 + m][n], 0, 0, 0);
    __builtin_amdgcn_s_setprio(0);
    __builtin_amdgcn_s_barrier();
    // ---- phase 2: ks=1, am 0..3, load bv(ks1)
#pragma unroll
    for (int i = 0; i < 4; ++i) {
      const int rowA = wr * 128 + i * 16 + lo16;
      av[i] = *(const bf16x8*)(bc + rowA * 128 + ((64 + hi4 * 16) ^ ((rowA & 7) << 4)));
      const int rowB = wc * 64 + i * 16 + lo16;
      bv[i] = *(const bf16x8*)(bc + 32768 + rowB * 128 + ((64 + hi4 * 16) ^ ((rowB & 7) << 4)));
    }
    __builtin_amdgcn_s_barrier();
    asm volatile("s_waitcnt lgkmcnt(0)" ::: "memory");
    __builtin_amdgcn_sched_barrier(0);
    __builtin_amdgcn_s_setprio(1);
#pragma unroll
    for (int m = 0; m < 4; ++m)
#pragma unroll
      for (int n = 0; n < 4; ++n)
        acc[m][n] = __builtin_amdgcn_mfma_f32_16x16x32_bf16(av[m], bv[n], acc[m][n], 0, 0, 0);
    __builtin_amdgcn_s_setprio(0);
    __builtin_amdgcn_s_barrier();
    // ---- phase 3: ks=1, am 4..7
#pragma unroll
    for (int i = 0; i < 4; ++i) {
      const int rowA = wr * 128 + (4 + i) * 16 + lo16;
      av[i] = *(const bf16x8*)(bc + rowA * 128 + ((64 + hi4 * 16) ^ ((rowA & 7) << 4)));
    }
    __builtin_amdgcn_s_barrier();
    asm volatile("s_waitcnt lgkmcnt(0)" ::: "memory");
    __builtin_amdgcn_sched_barrier(0);
    __builtin_amdgcn_s_setprio(1);
#pragma unroll
    for (int m = 0; m < 4; ++m)
#pragma unroll
      for (int n = 0; n < 4; ++n)
        acc[4 + m][n] = __builtin_amdgcn_mfma_f32_16x16x32_bf16(av[m], bv[n], acc[4 + m][n], 0, 0, 0);
    __builtin_amdgcn_s_setprio(0);
    if (kt < 7) asm volatile("s_waitcnt vmcnt(0)" ::: "memory");  // next K-tile landed (4 phases of slack)
    __builtin_amdgcn_s_barrier();
  }
}

// ---------------- K1: proj GEMM [1536x512]@[512x8192] per batch, fused epilogues ----------------
// 1536 blocks = 8 XCD x 192; XCD x owns batch x; 6 consecutive wg share one qT B-tile.
__global__ __launch_bounds__(512, 2) void k_proj(const u16* __restrict__ Wall, const u16* __restrict__ qT,
                                                 u16* __restrict__ qhT, u16* __restrict__ ek,
                                                 u16* __restrict__ vb, float* __restrict__ rowsum) {
  __shared__ __align__(16) char LDS[131072];   // 128 KB dbuf; epilogue reuses as 256x256 bf16 tile
  const int lid = blockIdx.x;
  const int wg = (lid & 7) * 192 + (lid >> 3);
  const int b = wg / 192, r = wg % 192;
  const int mt = r % 6, nt = r / 6;
  const int row0 = mt * 256, t0 = nt * 256;
  f32x4 acc[8][4] = {};
  gemm256(Wall + (size_t)row0 * CD, qT + ((size_t)b * TDIM + t0) * CD, LDS, acc);
  const int tid = threadIdx.x, lane = tid & 63, w = tid >> 6;
  const int wr = w >> 2, wc = w & 3, lo16 = lane & 15, hi4 = lane >> 4;
  char* lds = LDS;
  if (row0 < 512) {
    // ---- qh path: wave rows wr*128+[0,128) = two heads (am 0..3 | 4..7). softmax over head rows, *SCALE.
#pragma unroll
    for (int m = 0; m < 8; ++m)
#pragma unroll
      for (int n = 0; n < 4; ++n)
#pragma unroll
        for (int r2 = 0; r2 < 4; ++r2) acc[m][n][r2] = __expf(acc[m][n][r2]);
#pragma unroll
    for (int n = 0; n < 4; ++n) {
#pragma unroll
      for (int hm = 0; hm < 2; ++hm) {
        float s = 0.f;
#pragma unroll
        for (int m = 0; m < 4; ++m)
#pragma unroll
          for (int r2 = 0; r2 < 4; ++r2) s += acc[hm * 4 + m][n][r2];
        s += __shfl_xor(s, 16);
        s += __shfl_xor(s, 32);
        const float inv = SCALE / s;
#pragma unroll
        for (int m = 0; m < 4; ++m)
#pragma unroll
          for (int r2 = 0; r2 < 4; ++r2) acc[hm * 4 + m][n][r2] *= inv;
      }
    }
    // transposed LDS tile [t 256][c 256] bf16 (128 KB), 16B-gran XOR swizzle
#pragma unroll
    for (int m = 0; m < 8; ++m)
#pragma unroll
      for (int n = 0; n < 4; ++n) {
        const int tl = wc * 64 + n * 16 + lo16;
        const int cb2 = (wr * 128 + m * 16 + hi4 * 4) * 2;
        u16x4 p;
#pragma unroll
        for (int r2 = 0; r2 < 4; ++r2) p[r2] = f2bf(acc[m][n][r2]);
        *(u16x4*)(lds + tl * 512 + ((cb2 & ~15) ^ ((tl & 7) << 4)) + (cb2 & 8)) = p;
      }
    __syncthreads();
#pragma unroll
    for (int pp = 0; pp < 16; ++pp) {
      const int tr = pp * 16 + (tid >> 5), chk = tid & 31;
      const uint4 val = *(const uint4*)(lds + tr * 512 + ((chk * 16) ^ ((tr & 7) << 4)));
      *(uint4*)(qhT + ((size_t)b * TDIM + t0 + tr) * CD + row0 + chk * 8) = val;
    }
  } else {
    // ---- k path (exp + rowsum) or v path (plain)
    const bool isK = row0 < 1024;
    const int c0 = row0 - (isK ? 512 : 1024);
    if (isK) {
#pragma unroll
      for (int m = 0; m < 8; ++m)
#pragma unroll
        for (int n = 0; n < 4; ++n)
#pragma unroll
          for (int r2 = 0; r2 < 4; ++r2) acc[m][n][r2] = __expf(acc[m][n][r2]);
#pragma unroll
      for (int m = 0; m < 8; ++m)
#pragma unroll
        for (int r2 = 0; r2 < 4; ++r2) {
          float s = acc[m][0][r2] + acc[m][1][r2] + acc[m][2][r2] + acc[m][3][r2];
          s += __shfl_xor(s, 1); s += __shfl_xor(s, 2);
          s += __shfl_xor(s, 4); s += __shfl_xor(s, 8);
          if (lo16 == 0)
            unsafeAtomicAdd(rowsum + b * CD + c0 + wr * 128 + m * 16 + hi4 * 4 + r2, s);
        }
    }
    // natural LDS tile [c 256][t 256] bf16 (128 KB), 16B-gran XOR swizzle; 2B scattered ds_writes
#pragma unroll
    for (int m = 0; m < 8; ++m)
#pragma unroll
      for (int n = 0; n < 4; ++n) {
        const int tl2 = (wc * 64 + n * 16 + lo16) * 2;
#pragma unroll
        for (int r2 = 0; r2 < 4; ++r2) {
          const int cl = wr * 128 + m * 16 + hi4 * 4 + r2;
          *(u16*)(lds + cl * 512 + ((tl2 & ~15) ^ ((cl & 7) << 4)) + (tl2 & 15)) = f2bf(acc[m][n][r2]);
        }
      }
    __syncthreads();
    u16* dstb = isK ? ek : vb;
#pragma unroll
    for (int pp = 0; pp < 16; ++pp) {
      const int cr = pp * 16 + (tid >> 5), chk = tid & 31;
      const uint4 val = *(const uint4*)(lds + cr * 512 + ((chk * 16) ^ ((cr & 7) << 4)));
      *(uint4*)(dstb + ((size_t)b * CD + c0 + cr) * TDIM + t0 + chk * 8) = val;
    }
  }
}

// ---------------- K2: ctx_raw[b][h][d][e] += sum_t ek[d,t]*v[e,t] ----------------
__device__ __forceinline__ void ctx_stage(const u16* __restrict__ ekb, const u16* __restrict__ vbb,
                                          char* dst, int rr, int ch, int tb) {
#pragma unroll
  for (int i = 0; i < 8; ++i) {
    const int row = i * 8 + rr;
    const size_t goff = (size_t)row * TDIM + tb + ((ch ^ rr) << 3);
    gload16(ekb + goff, dst + i * 1024);
    gload16(vbb + goff, dst + 8192 + i * 1024);
  }
}

__global__ __launch_bounds__(256) void k_ctx(const u16* __restrict__ ek, const u16* __restrict__ vb,
                                             float* __restrict__ ctx) {
  __shared__ u16 SM[65536];        // 128 KB: 4 waves x 2 bufs x (ek 8KB + v 8KB)
  float (*red)[64] = (float(*)[64])SM;
  const int bh = blockIdx.y, tch = blockIdx.x;
  const int b = bh >> 3, h = bh & 7;
  const int tid = threadIdx.x, lane = tid & 63, w = tid >> 6;
  const int lo16 = lane & 15, hi4 = lane >> 4;
  char* wbase = (char*)SM + w * 32768;
  const u16* ekb = ek + ((size_t)(b * CD + h * 64)) * TDIM;
  const u16* vbb = vb + ((size_t)(b * CD + h * 64)) * TDIM;
  const int rr = lane >> 3, ch = lane & 7;
  f32x4 acc[4][4] = {};
  const int t00 = tch * 1024 + w * 256;
  ctx_stage(ekb, vbb, wbase, rr, ch, t00);
#pragma unroll 1
  for (int s = 0; s < 4; ++s) {
    char* curb = wbase + (s & 1) * 16384;
    if (s < 3) {
      ctx_stage(ekb, vbb, wbase + ((s & 1) ^ 1) * 16384, rr, ch, t00 + (s + 1) * 64);
      asm volatile("s_waitcnt vmcnt(16)" ::: "memory");
    } else {
      asm volatile("s_waitcnt vmcnt(0)" ::: "memory");
    }
    __builtin_amdgcn_sched_barrier(0);
#pragma unroll
    for (int ks = 0; ks < 2; ++ks) {
      bf16x8 av[4], bv[4];
#pragma unroll
      for (int am = 0; am < 4; ++am) {
        const int rowA = am * 16 + lo16;
        av[am] = *(const bf16x8*)(curb + rowA * 128 + ((ks * 64 + hi4 * 16) ^ ((rowA & 7) << 4)));
      }
#pragma unroll
      for (int an = 0; an < 4; ++an) {
        const int rowB = an * 16 + lo16;
        bv[an] = *(const bf16x8*)(curb + 8192 + rowB * 128 + ((ks * 64 + hi4 * 16) ^ ((rowB & 7) << 4)));
      }
#pragma unroll
      for (int am = 0; am < 4; ++am)
#pragma unroll
        for (int an = 0; an < 4; ++an)
          acc[am][an] = __builtin_amdgcn_mfma_f32_16x16x32_bf16(av[am], bv[an], acc[am][an], 0, 0, 0);
    }
  }
  for (int ww = 0; ww < 4; ++ww) {
    if (w == ww) {
#pragma unroll
      for (int am = 0; am < 4; ++am)
#pragma unroll
        for (int an = 0; an < 4; ++an)
#pragma unroll
          for (int r2 = 0; r2 < 4; ++r2) {
            const int d = am * 16 + hi4 * 4 + r2, e2 = an * 16 + lo16;
            if (ww == 0) red[d][e2] = acc[am][an][r2];
            else         red[d][e2] += acc[am][an][r2];
          }
    }
    __syncthreads();
  }
  float* cdst = ctx + (size_t)bh * 4096;
#pragma unroll
  for (int i = 0; i < 16; ++i) {
    const int idx = tid + 256 * i;
    unsafeAtomicAdd(cdst + idx, (&red[0][0])[idx]);
  }
}

// ---------------- K2b: Weff[b][o][64h+d] = sum_e Wout[o][64h+e] * ctx[d][e] / rowsum[d] ----------------
__global__ __launch_bounds__(256) void k_weff(const float* __restrict__ Wout, const float* __restrict__ ctx,
                                              const float* __restrict__ rowsum, u16* __restrict__ Weff) {
  __shared__ float cn[64][65];
  __shared__ float rsin[64];
  const int bh = blockIdx.y, b = bh >> 3, h = bh & 7;
  const int o0 = blockIdx.x * 64;
  const int tid = threadIdx.x;
  if (tid < 64) rsin[tid] = 1.f / rowsum[b * CD + h * 64 + tid];
  __syncthreads();
  const float* csrc = ctx + (size_t)bh * 4096;
#pragma unroll
  for (int i = 0; i < 16; ++i) {
    const int idx = tid + 256 * i;
    cn[idx >> 6][idx & 63] = csrc[idx] * rsin[idx >> 6];
  }
  __syncthreads();
  const int o = o0 + (tid >> 2), dq = (tid & 3) * 16;
  const float* wrow = Wout + (size_t)o * CD + h * 64;
  float a[16] = {};
  for (int e2 = 0; e2 < 64; ++e2) {
    const float wv = wrow[e2];
#pragma unroll
    for (int i = 0; i < 16; ++i) a[i] += wv * cn[dq + i][e2];
  }
  u16x8 p0, p1;
#pragma unroll
  for (int i = 0; i < 8; ++i) { p0[i] = f2bf(a[i]); p1[i] = f2bf(a[8 + i]); }
  u16* dst = Weff + ((size_t)(b * CD + o)) * CD + h * 64 + dq;
  *(u16x8*)dst = p0;
  *(u16x8*)(dst + 8) = p1;
}

// ---------------- K3: final[b][o][t] = Weff[b] @ qhT + b_out ----------------
// 512 blocks = 8 XCD x 64.
__global__ __launch_bounds__(512, 2) void k_final(const u16* __restrict__ Weff, const u16* __restrict__ qhT,
                                                  const float* __restrict__ bias, float* __restrict__ out) {
  __shared__ __align__(16) char LDS[131072];
  const int lid = blockIdx.x;
  const int wg = (lid & 7) * 64 + (lid >> 3);
  const int b = wg >> 6, r = wg & 63;
  const int mt = r & 1, nt = r >> 1;
  const int row0 = mt * 256, t0 = nt * 256;
  f32x4 acc[8][4] = {};
  gemm256(Weff + ((size_t)(b * CD + row0)) * CD, qhT + ((size_t)b * TDIM + t0) * CD, LDS, acc);
  const int tid = threadIdx.x, lane = tid & 63, w = tid >> 6;
  const int wr = w >> 2, wc = w & 3, lo16 = lane & 15, hi4 = lane >> 4;
#pragma unroll
  for (int m = 0; m < 8; ++m)
#pragma unroll
    for (int r2 = 0; r2 < 4; ++r2) {
      const int o = row0 + wr * 128 + m * 16 + hi4 * 4 + r2;
      const float bo = bias[o];
      float* orow = out + ((size_t)(b * CD + o)) * TDIM + t0 + wc * 64 + lo16;
#pragma unroll
      for (int n = 0; n < 4; ++n)
        orow[n * 16] = acc[m][n][r2] + bo;
    }
}

extern "C" void kernel_launch(void* const* d_in, const int* in_sizes, int n_in,
                              void* d_out, int out_size, void* d_ws, size_t ws_size,
                              hipStream_t stream) {
  const float* q    = (const float*)d_in[0];
  const float* Wq   = (const float*)d_in[1];
  const float* Wkv  = (const float*)d_in[2];
  const float* Wout = (const float*)d_in[3];
  const float* bout = (const float*)d_in[4];
  float* out = (float*)d_out;
  char* ws = (char*)d_ws;
  const size_t SZ = (size_t)NB * CD * TDIM * 2;   // 64 MiB per bf16 [8][512][8192] buffer
  u16* qT  = (u16*)ws;
  u16* qhT = (u16*)(ws + SZ);
  u16* ek  = (u16*)(ws + 2 * SZ);
  u16* vb  = (u16*)(ws + 3 * SZ);
  char* base = ws + 4 * SZ;
  u16* Wall   = (u16*)base;                       // 1.5 MB
  float* ctx  = (float*)(base + (2u << 20));      // 1 MB
  float* rsum = (float*)(base + (3u << 20));      // 16 KB
  u16* Weff   = (u16*)(base + (4u << 20));        // 4 MB
  (void)in_sizes; (void)n_in; (void)out_size; (void)ws_size;

  hipMemsetAsync(base + (2u << 20), 0, 2u << 20, stream);  // zero ctx + rowsum accumulators
  k_tq    <<<dim3(128, 8, 8), 256, 0, stream>>>(q, qT);
  k_cast_w<<<dim3(768), 256, 0, stream>>>(Wq, Wkv, Wall);
  k_proj  <<<dim3(1536), 512, 0, stream>>>(Wall, qT, qhT, ek, vb, rsum);
  k_ctx   <<<dim3(8, 64), 256, 0, stream>>>(ek, vb, ctx);
  k_weff  <<<dim3(8, 64), 256, 0, stream>>>(Wout, ctx, rsum, Weff);
  k_final <<<dim3(512), 512, 0, stream>>>(Weff, qhT, bout, out);
}

// Round 5
// 283.761 us; speedup vs baseline: 1.2131x; 1.2131x over previous
//
#include <hip/hip_runtime.h>

#define TDIM 8192
#define NB 8
#define CD 512
#define SCALE 0.125f

typedef unsigned int u32;
typedef unsigned short u16;
typedef __bf16 bf16;
typedef bf16 bf16x8 __attribute__((ext_vector_type(8)));
typedef float f32x4 __attribute__((ext_vector_type(4)));
typedef u16 u16x4 __attribute__((ext_vector_type(4)));
typedef u16 u16x8 __attribute__((ext_vector_type(8)));

__device__ __forceinline__ u16 f2bf(float f) {
  u32 u = __float_as_uint(f);
  return (u16)((u + 0x7FFFu + ((u >> 16) & 1u)) >> 16);
}

__device__ __forceinline__ void gload16(const void* g, void* l) {
  __builtin_amdgcn_global_load_lds((const __attribute__((address_space(1))) u32*)g,
                                   (__attribute__((address_space(3))) u32*)l, 16, 0, 0);
}

// ---------------- K0: transpose + cast q: [b][c][t] f32 -> qT [b][t][c] bf16 ----------------
__global__ __launch_bounds__(256) void k_tq(const float* __restrict__ q, u16* __restrict__ qT) {
  __shared__ float tile[64][65];
  const int b = blockIdx.z, cb = blockIdx.y * 64, tb = blockIdx.x * 64;
  const int tid = threadIdx.x, r = tid >> 2, qd = tid & 3;
  const float* src = q + ((size_t)(b * CD + cb + r)) * TDIM + tb;
#pragma unroll
  for (int j = 0; j < 4; ++j) {
    const float4 v = *(const float4*)(src + j * 16 + qd * 4);
    tile[r][j * 16 + qd * 4 + 0] = v.x;
    tile[r][j * 16 + qd * 4 + 1] = v.y;
    tile[r][j * 16 + qd * 4 + 2] = v.z;
    tile[r][j * 16 + qd * 4 + 3] = v.w;
  }
  __syncthreads();
  u16x8 o0, o1;
#pragma unroll
  for (int i = 0; i < 8; ++i) o0[i] = f2bf(tile[qd * 16 + i][r]);
#pragma unroll
  for (int i = 0; i < 8; ++i) o1[i] = f2bf(tile[qd * 16 + 8 + i][r]);
  u16* dst = qT + ((size_t)b * TDIM + tb + r) * CD + cb + qd * 16;
  *(u16x8*)dst = o0;
  *(u16x8*)(dst + 8) = o1;
}

// ---------------- cast weights: Wq (512x512) ++ Wkv (1024x512) -> Wall bf16 ----------------
__global__ __launch_bounds__(256) void k_cast_w(const float* __restrict__ Wq, const float* __restrict__ Wkv,
                                                u16* __restrict__ Wall) {
  const int idx = (blockIdx.x * 256 + threadIdx.x) * 4;
  float4 v;
  if (idx < 512 * 512) v = *(const float4*)(Wq + idx);
  else                 v = *(const float4*)(Wkv + (idx - 512 * 512));
  u16x4 p;
  p[0] = f2bf(v.x); p[1] = f2bf(v.y); p[2] = f2bf(v.z); p[3] = f2bf(v.w);
  *(u16x4*)(Wall + idx) = p;
}

// ============ 256x128 GEMM core, BK=64, 8 waves (4M x 2N, wave=64x64), ring-3 LDS, counted vmcnt ============
// A rows are given per-wave (Aw = base of this wave's 32-row strip); B[n][k] 128 rows.
// Ring buf b: A at b*49152 (32 KB), B at +32768 (16 KB). K-tile k in buf[k%3]; k+2 staged into
// buf[(k+2)%3]. vmcnt(6) once per K-tile; vmcnt(0) only at kt=6.
__device__ __forceinline__ void stageA(const u16* __restrict__ Aw, char* buf, int w, int rr, int ch, int kt) {
#pragma unroll
  for (int i = 0; i < 4; ++i)
    gload16(Aw + (size_t)(i * 8 + rr) * CD + kt * 64 + ((ch ^ rr) << 3), buf + (w * 4 + i) * 1024);
}
__device__ __forceinline__ void stageB(const u16* __restrict__ B, char* buf, int w, int rr, int ch, int kt) {
#pragma unroll
  for (int i = 0; i < 2; ++i) {
    const int row = (w * 2 + i) * 8 + rr;
    gload16(B + (size_t)row * CD + kt * 64 + ((ch ^ rr) << 3), buf + 32768 + (w * 2 + i) * 1024);
  }
}

__device__ __forceinline__ void gemm256(const u16* __restrict__ Aw, const u16* __restrict__ B,
                                        char* lds, f32x4 (&acc)[4][4]) {
  const int tid = threadIdx.x, lane = tid & 63, w = tid >> 6;
  const int wr = w >> 1, wc = w & 1;
  const int rr = lane >> 3, ch = lane & 7;
  const int lo16 = lane & 15, hi4 = lane >> 4;
  stageA(Aw, lds, w, rr, ch, 0);          stageB(B, lds, w, rr, ch, 0);
  stageA(Aw, lds + 49152, w, rr, ch, 1);  stageB(B, lds + 49152, w, rr, ch, 1);
  asm volatile("s_waitcnt vmcnt(6)" ::: "memory");   // K-tile 0 landed; K-tile 1 in flight
  __builtin_amdgcn_s_barrier();
#pragma unroll 1
  for (int kt = 0; kt < 8; ++kt) {
    char* bc = lds + (kt % 3) * 49152;
    char* bn = lds + ((kt + 2) % 3) * 49152;
#pragma unroll
    for (int ks = 0; ks < 2; ++ks) {
      bf16x8 av[4], bv[4];
#pragma unroll
      for (int am = 0; am < 4; ++am) {
        const int rowA = wr * 64 + am * 16 + lo16;
        av[am] = *(const bf16x8*)(bc + rowA * 128 + ((ks * 64 + hi4 * 16) ^ ((rowA & 7) << 4)));
      }
#pragma unroll
      for (int an = 0; an < 4; ++an) {
        const int rowB = wc * 64 + an * 16 + lo16;
        bv[an] = *(const bf16x8*)(bc + 32768 + rowB * 128 + ((ks * 64 + hi4 * 16) ^ ((rowB & 7) << 4)));
      }
      if (kt < 6) {
        if (ks == 0) stageA(Aw, bn, w, rr, ch, kt + 2);
        else         stageB(B, bn, w, rr, ch, kt + 2);
      }
      if (ks == 1) {
        if (kt < 6)       asm volatile("s_waitcnt vmcnt(6)" ::: "memory");
        else if (kt == 6) asm volatile("s_waitcnt vmcnt(0)" ::: "memory");
      }
      __builtin_amdgcn_s_barrier();
      asm volatile("s_waitcnt lgkmcnt(0)" ::: "memory");
      __builtin_amdgcn_sched_barrier(0);
      __builtin_amdgcn_s_setprio(1);
#pragma unroll
      for (int am = 0; am < 4; ++am)
#pragma unroll
        for (int an = 0; an < 4; ++an)
          acc[am][an] = __builtin_amdgcn_mfma_f32_16x16x32_bf16(av[am], bv[an], acc[am][an], 0, 0, 0);
      __builtin_amdgcn_s_setprio(0);
      __builtin_amdgcn_s_barrier();
    }
  }
}

// ---------------- K1: proj GEMM + fused softmax/exp/rowsum + fused ctx accumulation ----------------
// M-tiles per batch: mt 0,1 = qh rows mt*256; mt 2..5 = paired (k rows j*128..+128, v rows j*128..+128),
// j = mt-2, i.e. heads 2j,2j+1. kv-blocks compute ctx[h][d][e] += ek@v^T over their 128-t span (LDS
// GEMM) and atomically accumulate into global f32 ctx — ek/vb never hit HBM, k_ctx eliminated.
// 3072 blocks = 8 XCD x 384; XCD x owns batch x; 6 consecutive wg share one qT B-tile.
__global__ __launch_bounds__(512, 2) void k_proj(const u16* __restrict__ Wall, const u16* __restrict__ qT,
                                                 u16* __restrict__ qhT, float* __restrict__ ctx,
                                                 float* __restrict__ rowsum) {
  __shared__ __align__(16) char LDS[147456];   // 144 KB ring-3; epilogue reuses first 64 KB
  const int lid = blockIdx.x;
  const int wg = (lid & 7) * 384 + (lid >> 3);
  const int b = wg / 384, r = wg % 384;
  const int mt = r % 6, nt = r / 6;
  const int t0 = nt * 128;
  const int tid = threadIdx.x, lane = tid & 63, w = tid >> 6;
  const int wr = w >> 1, wc = w & 1, lo16 = lane & 15, hi4 = lane >> 4;
  const bool isQH = mt < 2;
  const int j = mt - 2;
  const u16* Aw;
  if (isQH) Aw = Wall + (size_t)(mt * 256 + w * 32) * CD;
  else      Aw = Wall + (size_t)((w < 4) ? (512 + j * 128 + w * 32)
                                         : (1024 + j * 128 + (w - 4) * 32)) * CD;
  f32x4 acc[4][4] = {};
  gemm256(Aw, qT + ((size_t)b * TDIM + t0) * CD, LDS, acc);
  char* lds = LDS;
  if (isQH) {
    const int row0 = mt * 256;
    // ---- qh path: wave owns head (row0/64 + wr): 64 rows. softmax over rows per column, *SCALE.
#pragma unroll
    for (int am = 0; am < 4; ++am)
#pragma unroll
      for (int an = 0; an < 4; ++an)
#pragma unroll
        for (int r2 = 0; r2 < 4; ++r2) acc[am][an][r2] = __expf(acc[am][an][r2]);
#pragma unroll
    for (int an = 0; an < 4; ++an) {
      float s = 0.f;
#pragma unroll
      for (int am = 0; am < 4; ++am)
#pragma unroll
        for (int r2 = 0; r2 < 4; ++r2) s += acc[am][an][r2];
      s += __shfl_xor(s, 16);
      s += __shfl_xor(s, 32);
      const float inv = SCALE / s;
#pragma unroll
      for (int am = 0; am < 4; ++am)
#pragma unroll
        for (int r2 = 0; r2 < 4; ++r2) acc[am][an][r2] *= inv;
    }
    // transposed LDS tile [t 128][c 256] bf16 (64 KB), 16B-gran XOR swizzle
#pragma unroll
    for (int am = 0; am < 4; ++am)
#pragma unroll
      for (int an = 0; an < 4; ++an) {
        const int tl = wc * 64 + an * 16 + lo16;
        const int cb2 = (wr * 64 + am * 16 + hi4 * 4) * 2;
        u16x4 p;
#pragma unroll
        for (int r2 = 0; r2 < 4; ++r2) p[r2] = f2bf(acc[am][an][r2]);
        *(u16x4*)(lds + tl * 512 + ((cb2 & ~15) ^ ((tl & 7) << 4)) + (cb2 & 8)) = p;
      }
    __syncthreads();
#pragma unroll
    for (int pp = 0; pp < 8; ++pp) {
      const int tr = pp * 16 + (tid >> 5), chk = tid & 31;
      const uint4 val = *(const uint4*)(lds + tr * 512 + ((chk * 16) ^ ((tr & 7) << 4)));
      *(uint4*)(qhT + ((size_t)b * TDIM + t0 + tr) * CD + row0 + chk * 8) = val;
    }
  } else {
    // ---- kv path: tile rows 0..127 = k rows (c = j*128 + row), 128..255 = v rows (same c).
    if (wr < 2) {   // k-half waves: exp + rowsum
#pragma unroll
      for (int am = 0; am < 4; ++am)
#pragma unroll
        for (int an = 0; an < 4; ++an)
#pragma unroll
          for (int r2 = 0; r2 < 4; ++r2) acc[am][an][r2] = __expf(acc[am][an][r2]);
#pragma unroll
      for (int am = 0; am < 4; ++am)
#pragma unroll
        for (int r2 = 0; r2 < 4; ++r2) {
          float s = acc[am][0][r2] + acc[am][1][r2] + acc[am][2][r2] + acc[am][3][r2];
          s += __shfl_xor(s, 1); s += __shfl_xor(s, 2);
          s += __shfl_xor(s, 4); s += __shfl_xor(s, 8);
          if (lo16 == 0)
            unsafeAtomicAdd(rowsum + b * CD + j * 128 + wr * 64 + am * 16 + hi4 * 4 + r2, s);
        }
    }
    // natural LDS tile [row 256][t 128] bf16 (64 KB), 16B-gran XOR swizzle; 2B scattered writes
#pragma unroll
    for (int am = 0; am < 4; ++am)
#pragma unroll
      for (int an = 0; an < 4; ++an) {
        const int tl2 = (wc * 64 + an * 16 + lo16) * 2;
#pragma unroll
        for (int r2 = 0; r2 < 4; ++r2) {
          const int cl = wr * 64 + am * 16 + hi4 * 4 + r2;
          *(u16*)(lds + cl * 256 + ((tl2 & ~15) ^ ((cl & 7) << 4)) + (tl2 & 15)) = f2bf(acc[am][an][r2]);
        }
      }
    __syncthreads();
    // ctx GEMM from LDS: wave w -> head hw = w>>2 (global j*2+hw), quadrant d0=(w&1)*32, e0=((w>>1)&1)*32.
    // ek rows at tile row hw*64+d, v rows at 128+hw*64+e; contract over this block's 128 t.
    const int hw = w >> 2, d0 = (w & 1) * 32, e0 = ((w >> 1) & 1) * 32;
    f32x4 cacc[2][2] = {};
#pragma unroll
    for (int tk = 0; tk < 4; ++tk) {
      bf16x8 ea[2], vv[2];
#pragma unroll
      for (int dm = 0; dm < 2; ++dm) {
        const int rowE = hw * 64 + d0 + dm * 16 + lo16;
        ea[dm] = *(const bf16x8*)(lds + rowE * 256 + ((tk * 64 + hi4 * 16) ^ ((rowE & 7) << 4)));
      }
#pragma unroll
      for (int de = 0; de < 2; ++de) {
        const int rowV = 128 + hw * 64 + e0 + de * 16 + lo16;
        vv[de] = *(const bf16x8*)(lds + rowV * 256 + ((tk * 64 + hi4 * 16) ^ ((rowV & 7) << 4)));
      }
#pragma unroll
      for (int dm = 0; dm < 2; ++dm)
#pragma unroll
        for (int de = 0; de < 2; ++de)
          cacc[dm][de] = __builtin_amdgcn_mfma_f32_16x16x32_bf16(ea[dm], vv[de], cacc[dm][de], 0, 0, 0);
    }
    float* cdst = ctx + ((size_t)(b * 8 + j * 2 + hw)) * 4096;
#pragma unroll
    for (int dm = 0; dm < 2; ++dm)
#pragma unroll
      for (int de = 0; de < 2; ++de)
#pragma unroll
        for (int r2 = 0; r2 < 4; ++r2)
          unsafeAtomicAdd(cdst + (d0 + dm * 16 + hi4 * 4 + r2) * 64 + e0 + de * 16 + lo16,
                          cacc[dm][de][r2]);
  }
}

// ---------------- K2b: Weff[b][o][64h+d] = sum_e Wout[o][64h+e] * ctx[d][e] / rowsum[d] ----------------
__global__ __launch_bounds__(256) void k_weff(const float* __restrict__ Wout, const float* __restrict__ ctx,
                                              const float* __restrict__ rowsum, u16* __restrict__ Weff) {
  __shared__ float cn[64][65];
  __shared__ float rsin[64];
  const int bh = blockIdx.y, b = bh >> 3, h = bh & 7;
  const int o0 = blockIdx.x * 64;
  const int tid = threadIdx.x;
  if (tid < 64) rsin[tid] = 1.f / rowsum[b * CD + h * 64 + tid];
  __syncthreads();
  const float* csrc = ctx + (size_t)bh * 4096;
#pragma unroll
  for (int i = 0; i < 16; ++i) {
    const int idx = tid + 256 * i;
    cn[idx >> 6][idx & 63] = csrc[idx] * rsin[idx >> 6];
  }
  __syncthreads();
  const int o = o0 + (tid >> 2), dq = (tid & 3) * 16;
  const float* wrow = Wout + (size_t)o * CD + h * 64;
  float a[16] = {};
  for (int e2 = 0; e2 < 64; ++e2) {
    const float wv = wrow[e2];
#pragma unroll
    for (int i = 0; i < 16; ++i) a[i] += wv * cn[dq + i][e2];
  }
  u16x8 p0, p1;
#pragma unroll
  for (int i = 0; i < 8; ++i) { p0[i] = f2bf(a[i]); p1[i] = f2bf(a[8 + i]); }
  u16* dst = Weff + ((size_t)(b * CD + o)) * CD + h * 64 + dq;
  *(u16x8*)dst = p0;
  *(u16x8*)(dst + 8) = p1;
}

// ---------------- K3: final[b][o][t] = Weff[b] @ qhT + b_out ----------------
// 1024 blocks = 8 XCD x 128.
__global__ __launch_bounds__(512, 2) void k_final(const u16* __restrict__ Weff, const u16* __restrict__ qhT,
                                                  const float* __restrict__ bias, float* __restrict__ out) {
  __shared__ __align__(16) char LDS[147456];
  const int lid = blockIdx.x;
  const int wg = (lid & 7) * 128 + (lid >> 3);
  const int b = wg >> 7, r = wg & 127;
  const int mt = r & 1, nt = r >> 1;
  const int row0 = mt * 256, t0 = nt * 128;
  const int tid = threadIdx.x, lane = tid & 63, w = tid >> 6;
  const int wr = w >> 1, wc = w & 1, lo16 = lane & 15, hi4 = lane >> 4;
  const u16* Aw = Weff + ((size_t)(b * CD + row0 + w * 32)) * CD;
  f32x4 acc[4][4] = {};
  gemm256(Aw, qhT + ((size_t)b * TDIM + t0) * CD, LDS, acc);
#pragma unroll
  for (int am = 0; am < 4; ++am)
#pragma unroll
    for (int r2 = 0; r2 < 4; ++r2) {
      const int o = row0 + wr * 64 + am * 16 + hi4 * 4 + r2;
      const float bo = bias[o];
      float* orow = out + ((size_t)(b * CD + o)) * TDIM + t0 + wc * 64 + lo16;
#pragma unroll
      for (int an = 0; an < 4; ++an)
        orow[an * 16] = acc[am][an][r2] + bo;
    }
}

extern "C" void kernel_launch(void* const* d_in, const int* in_sizes, int n_in,
                              void* d_out, int out_size, void* d_ws, size_t ws_size,
                              hipStream_t stream) {
  const float* q    = (const float*)d_in[0];
  const float* Wq   = (const float*)d_in[1];
  const float* Wkv  = (const float*)d_in[2];
  const float* Wout = (const float*)d_in[3];
  const float* bout = (const float*)d_in[4];
  float* out = (float*)d_out;
  char* ws = (char*)d_ws;
  const size_t SZ = (size_t)NB * CD * TDIM * 2;   // 64 MiB per bf16 [8][512][8192] buffer
  u16* qT  = (u16*)ws;
  u16* qhT = (u16*)(ws + SZ);
  char* base = ws + 2 * SZ;
  u16* Wall   = (u16*)base;                       // 1.5 MB
  float* ctx  = (float*)(base + (2u << 20));      // 1 MB
  float* rsum = (float*)(base + (3u << 20));      // 16 KB
  u16* Weff   = (u16*)(base + (4u << 20));        // 4 MB
  (void)in_sizes; (void)n_in; (void)out_size; (void)ws_size;

  hipMemsetAsync(base + (2u << 20), 0, 2u << 20, stream);  // zero ctx + rowsum accumulators
  k_tq    <<<dim3(128, 8, 8), 256, 0, stream>>>(q, qT);
  k_cast_w<<<dim3(768), 256, 0, stream>>>(Wq, Wkv, Wall);
  k_proj  <<<dim3(3072), 512, 0, stream>>>(Wall, qT, qhT, ctx, rsum);
  k_weff  <<<dim3(8, 64), 256, 0, stream>>>(Wout, ctx, rsum, Weff);
  k_final <<<dim3(1024), 512, 0, stream>>>(Weff, qhT, bout, out);
}

// Round 6
// 252.749 us; speedup vs baseline: 1.3620x; 1.1227x over previous
//
#include <hip/hip_runtime.h>

#define TDIM 8192
#define NB 8
#define CD 512
#define SCALE 0.125f

typedef unsigned int u32;
typedef unsigned short u16;
typedef __bf16 bf16;
typedef bf16 bf16x8 __attribute__((ext_vector_type(8)));
typedef float f32x4 __attribute__((ext_vector_type(4)));
typedef u16 u16x4 __attribute__((ext_vector_type(4)));
typedef u16 u16x8 __attribute__((ext_vector_type(8)));

__device__ __forceinline__ u16 f2bf(float f) {
  u32 u = __float_as_uint(f);
  return (u16)((u + 0x7FFFu + ((u >> 16) & 1u)) >> 16);
}

__device__ __forceinline__ void gload16(const void* g, void* l) {
  __builtin_amdgcn_global_load_lds((const __attribute__((address_space(1))) u32*)g,
                                   (__attribute__((address_space(3))) u32*)l, 16, 0, 0);
}

// ---------------- K0: transpose + cast q: [b][c][t] f32 -> qT [b][t][c] bf16 ----------------
__global__ __launch_bounds__(256) void k_tq(const float* __restrict__ q, u16* __restrict__ qT) {
  __shared__ float tile[64][65];
  const int b = blockIdx.z, cb = blockIdx.y * 64, tb = blockIdx.x * 64;
  const int tid = threadIdx.x, r = tid >> 2, qd = tid & 3;
  const float* src = q + ((size_t)(b * CD + cb + r)) * TDIM + tb;
#pragma unroll
  for (int j = 0; j < 4; ++j) {
    const float4 v = *(const float4*)(src + j * 16 + qd * 4);
    tile[r][j * 16 + qd * 4 + 0] = v.x;
    tile[r][j * 16 + qd * 4 + 1] = v.y;
    tile[r][j * 16 + qd * 4 + 2] = v.z;
    tile[r][j * 16 + qd * 4 + 3] = v.w;
  }
  __syncthreads();
  u16x8 o0, o1;
#pragma unroll
  for (int i = 0; i < 8; ++i) o0[i] = f2bf(tile[qd * 16 + i][r]);
#pragma unroll
  for (int i = 0; i < 8; ++i) o1[i] = f2bf(tile[qd * 16 + 8 + i][r]);
  u16* dst = qT + ((size_t)b * TDIM + tb + r) * CD + cb + qd * 16;
  *(u16x8*)dst = o0;
  *(u16x8*)(dst + 8) = o1;
}

// ---------------- cast weights: Wq (512x512) ++ Wkv (1024x512) -> Wall bf16 ----------------
__global__ __launch_bounds__(256) void k_cast_w(const float* __restrict__ Wq, const float* __restrict__ Wkv,
                                                u16* __restrict__ Wall) {
  const int idx = (blockIdx.x * 256 + threadIdx.x) * 4;
  float4 v;
  if (idx < 512 * 512) v = *(const float4*)(Wq + idx);
  else                 v = *(const float4*)(Wkv + (idx - 512 * 512));
  u16x4 p;
  p[0] = f2bf(v.x); p[1] = f2bf(v.y); p[2] = f2bf(v.z); p[3] = f2bf(v.w);
  *(u16x4*)(Wall + idx) = p;
}

// ============ 256x128 GEMM core, BK=64, 8 waves (4M x 2N, wave=64x64), ring-3 LDS ============
// Barrier-light schedule: per K-tile { vmcnt(6) ; s_barrier ; issue stage(kt+2) ; 16 ds_read +
// 32 MFMA compiler-scheduled }. Stage(kt+2) is issued AFTER barrier(kt), which guarantees all
// waves consumed kt-1's reads of that buffer. vmcnt(0) only at kt=7. Full unroll (static ring offs).
__device__ __forceinline__ void stageA(const u16* __restrict__ Aw, char* buf, int w, int rr, int ch, int kt) {
#pragma unroll
  for (int i = 0; i < 4; ++i)
    gload16(Aw + (size_t)(i * 8 + rr) * CD + kt * 64 + ((ch ^ rr) << 3), buf + (w * 4 + i) * 1024);
}
__device__ __forceinline__ void stageB(const u16* __restrict__ B, char* buf, int w, int rr, int ch, int kt) {
#pragma unroll
  for (int i = 0; i < 2; ++i) {
    const int row = (w * 2 + i) * 8 + rr;
    gload16(B + (size_t)row * CD + kt * 64 + ((ch ^ rr) << 3), buf + 32768 + (w * 2 + i) * 1024);
  }
}

__device__ __forceinline__ void gemm256(const u16* __restrict__ Aw, const u16* __restrict__ B,
                                        char* lds, f32x4 (&acc)[4][4]) {
  const int tid = threadIdx.x, lane = tid & 63, w = tid >> 6;
  const int wr = w >> 1, wc = w & 1;
  const int rr = lane >> 3, ch = lane & 7;
  const int lo16 = lane & 15, hi4 = lane >> 4;
  stageA(Aw, lds, w, rr, ch, 0);          stageB(B, lds, w, rr, ch, 0);
  stageA(Aw, lds + 49152, w, rr, ch, 1);  stageB(B, lds + 49152, w, rr, ch, 1);
#pragma unroll
  for (int kt = 0; kt < 8; ++kt) {
    if (kt < 7) asm volatile("s_waitcnt vmcnt(6)" ::: "memory");   // stage(kt) landed; stage(kt+1) in flight
    else        asm volatile("s_waitcnt vmcnt(0)" ::: "memory");   // stage(7) landed (issued at kt=5)
    __builtin_amdgcn_s_barrier();
    char* bc = lds + (kt % 3) * 49152;
    if (kt < 6) {            // safe: all waves finished kt-1 reads of this buffer (barrier above)
      char* bn = lds + ((kt + 2) % 3) * 49152;
      stageA(Aw, bn, w, rr, ch, kt + 2);
      stageB(B, bn, w, rr, ch, kt + 2);
    }
#pragma unroll
    for (int ks = 0; ks < 2; ++ks) {
      bf16x8 av[4], bv[4];
#pragma unroll
      for (int am = 0; am < 4; ++am) {
        const int rowA = wr * 64 + am * 16 + lo16;
        av[am] = *(const bf16x8*)(bc + rowA * 128 + ((ks * 64 + hi4 * 16) ^ ((rowA & 7) << 4)));
      }
#pragma unroll
      for (int an = 0; an < 4; ++an) {
        const int rowB = wc * 64 + an * 16 + lo16;
        bv[an] = *(const bf16x8*)(bc + 32768 + rowB * 128 + ((ks * 64 + hi4 * 16) ^ ((rowB & 7) << 4)));
      }
#pragma unroll
      for (int am = 0; am < 4; ++am)
#pragma unroll
        for (int an = 0; an < 4; ++an)
          acc[am][an] = __builtin_amdgcn_mfma_f32_16x16x32_bf16(av[am], bv[an], acc[am][an], 0, 0, 0);
    }
  }
  __syncthreads();   // all waves done reading ring before epilogue reuses LDS
}

// ---------------- K1: proj GEMM + fused softmax/exp/rowsum + fused ctx accumulation ----------------
// M-tiles per batch: mt 0,1 = qh rows mt*256; mt 2..5 = paired (k rows j*128..+128, v rows j*128..+128),
// j = mt-2, i.e. heads 2j,2j+1. kv-blocks compute ctx[h][d][e] += ek@v^T over their 128-t span (LDS
// GEMM) and atomically accumulate into global f32 ctx — ek/vb never hit HBM.
// 3072 blocks = 8 XCD x 384; XCD x owns batch x; 6 consecutive wg share one qT B-tile.
__global__ __launch_bounds__(512, 2) void k_proj(const u16* __restrict__ Wall, const u16* __restrict__ qT,
                                                 u16* __restrict__ qhT, float* __restrict__ ctx,
                                                 float* __restrict__ rowsum) {
  __shared__ __align__(16) char LDS[147456];   // 144 KB ring-3; epilogue reuses first 64 KB
  const int lid = blockIdx.x;
  const int wg = (lid & 7) * 384 + (lid >> 3);
  const int b = wg / 384, r = wg % 384;
  const int mt = r % 6, nt = r / 6;
  const int t0 = nt * 128;
  const int tid = threadIdx.x, lane = tid & 63, w = tid >> 6;
  const int wr = w >> 1, wc = w & 1, lo16 = lane & 15, hi4 = lane >> 4;
  const bool isQH = mt < 2;
  const int j = mt - 2;
  const u16* Aw;
  if (isQH) Aw = Wall + (size_t)(mt * 256 + w * 32) * CD;
  else      Aw = Wall + (size_t)((w < 4) ? (512 + j * 128 + w * 32)
                                         : (1024 + j * 128 + (w - 4) * 32)) * CD;
  f32x4 acc[4][4] = {};
  gemm256(Aw, qT + ((size_t)b * TDIM + t0) * CD, LDS, acc);
  char* lds = LDS;
  if (isQH) {
    const int row0 = mt * 256;
    // ---- qh path: wave owns head (row0/64 + wr): 64 rows. softmax over rows per column, *SCALE.
#pragma unroll
    for (int am = 0; am < 4; ++am)
#pragma unroll
      for (int an = 0; an < 4; ++an)
#pragma unroll
        for (int r2 = 0; r2 < 4; ++r2) acc[am][an][r2] = __expf(acc[am][an][r2]);
#pragma unroll
    for (int an = 0; an < 4; ++an) {
      float s = 0.f;
#pragma unroll
      for (int am = 0; am < 4; ++am)
#pragma unroll
        for (int r2 = 0; r2 < 4; ++r2) s += acc[am][an][r2];
      s += __shfl_xor(s, 16);
      s += __shfl_xor(s, 32);
      const float inv = SCALE / s;
#pragma unroll
      for (int am = 0; am < 4; ++am)
#pragma unroll
        for (int r2 = 0; r2 < 4; ++r2) acc[am][an][r2] *= inv;
    }
    // transposed LDS tile [t 128][c 256] bf16 (64 KB), 16B-gran XOR swizzle
#pragma unroll
    for (int am = 0; am < 4; ++am)
#pragma unroll
      for (int an = 0; an < 4; ++an) {
        const int tl = wc * 64 + an * 16 + lo16;
        const int cb2 = (wr * 64 + am * 16 + hi4 * 4) * 2;
        u16x4 p;
#pragma unroll
        for (int r2 = 0; r2 < 4; ++r2) p[r2] = f2bf(acc[am][an][r2]);
        *(u16x4*)(lds + tl * 512 + ((cb2 & ~15) ^ ((tl & 7) << 4)) + (cb2 & 8)) = p;
      }
    __syncthreads();
#pragma unroll
    for (int pp = 0; pp < 8; ++pp) {
      const int tr = pp * 16 + (tid >> 5), chk = tid & 31;
      const uint4 val = *(const uint4*)(lds + tr * 512 + ((chk * 16) ^ ((tr & 7) << 4)));
      *(uint4*)(qhT + ((size_t)b * TDIM + t0 + tr) * CD + row0 + chk * 8) = val;
    }
  } else {
    // ---- kv path: tile rows 0..127 = k rows (c = j*128 + row), 128..255 = v rows (same c).
    if (wr < 2) {   // k-half waves: exp + rowsum
#pragma unroll
      for (int am = 0; am < 4; ++am)
#pragma unroll
        for (int an = 0; an < 4; ++an)
#pragma unroll
          for (int r2 = 0; r2 < 4; ++r2) acc[am][an][r2] = __expf(acc[am][an][r2]);
#pragma unroll
      for (int am = 0; am < 4; ++am)
#pragma unroll
        for (int r2 = 0; r2 < 4; ++r2) {
          float s = acc[am][0][r2] + acc[am][1][r2] + acc[am][2][r2] + acc[am][3][r2];
          s += __shfl_xor(s, 1); s += __shfl_xor(s, 2);
          s += __shfl_xor(s, 4); s += __shfl_xor(s, 8);
          if (lo16 == 0)
            unsafeAtomicAdd(rowsum + b * CD + j * 128 + wr * 64 + am * 16 + hi4 * 4 + r2, s);
        }
    }
    // natural LDS tile [row 256][t 128] bf16 (64 KB), 16B-gran XOR swizzle; 2B scattered writes
#pragma unroll
    for (int am = 0; am < 4; ++am)
#pragma unroll
      for (int an = 0; an < 4; ++an) {
        const int tl2 = (wc * 64 + an * 16 + lo16) * 2;
#pragma unroll
        for (int r2 = 0; r2 < 4; ++r2) {
          const int cl = wr * 64 + am * 16 + hi4 * 4 + r2;
          *(u16*)(lds + cl * 256 + ((tl2 & ~15) ^ ((cl & 7) << 4)) + (tl2 & 15)) = f2bf(acc[am][an][r2]);
        }
      }
    __syncthreads();
    // ctx GEMM from LDS: wave w -> head hw = w>>2 (global j*2+hw), quadrant d0=(w&1)*32, e0=((w>>1)&1)*32.
    const int hw = w >> 2, d0 = (w & 1) * 32, e0 = ((w >> 1) & 1) * 32;
    f32x4 cacc[2][2] = {};
#pragma unroll
    for (int tk = 0; tk < 4; ++tk) {
      bf16x8 ea[2], vv[2];
#pragma unroll
      for (int dm = 0; dm < 2; ++dm) {
        const int rowE = hw * 64 + d0 + dm * 16 + lo16;
        ea[dm] = *(const bf16x8*)(lds + rowE * 256 + ((tk * 64 + hi4 * 16) ^ ((rowE & 7) << 4)));
      }
#pragma unroll
      for (int de = 0; de < 2; ++de) {
        const int rowV = 128 + hw * 64 + e0 + de * 16 + lo16;
        vv[de] = *(const bf16x8*)(lds + rowV * 256 + ((tk * 64 + hi4 * 16) ^ ((rowV & 7) << 4)));
      }
#pragma unroll
      for (int dm = 0; dm < 2; ++dm)
#pragma unroll
        for (int de = 0; de < 2; ++de)
          cacc[dm][de] = __builtin_amdgcn_mfma_f32_16x16x32_bf16(ea[dm], vv[de], cacc[dm][de], 0, 0, 0);
    }
    float* cdst = ctx + ((size_t)(b * 8 + j * 2 + hw)) * 4096;
#pragma unroll
    for (int dm = 0; dm < 2; ++dm)
#pragma unroll
      for (int de = 0; de < 2; ++de)
#pragma unroll
        for (int r2 = 0; r2 < 4; ++r2)
          unsafeAtomicAdd(cdst + (d0 + dm * 16 + hi4 * 4 + r2) * 64 + e0 + de * 16 + lo16,
                          cacc[dm][de][r2]);
  }
}

// ---------------- K2b: Weff[b][o][64h+d] = sum_e Wout[o][64h+e] * ctx[d][e] / rowsum[d] ----------------
__global__ __launch_bounds__(256) void k_weff(const float* __restrict__ Wout, const float* __restrict__ ctx,
                                              const float* __restrict__ rowsum, u16* __restrict__ Weff) {
  __shared__ float cn[64][65];
  __shared__ float rsin[64];
  const int bh = blockIdx.y, b = bh >> 3, h = bh & 7;
  const int o0 = blockIdx.x * 64;
  const int tid = threadIdx.x;
  if (tid < 64) rsin[tid] = 1.f / rowsum[b * CD + h * 64 + tid];
  __syncthreads();
  const float* csrc = ctx + (size_t)bh * 4096;
#pragma unroll
  for (int i = 0; i < 16; ++i) {
    const int idx = tid + 256 * i;
    cn[idx >> 6][idx & 63] = csrc[idx] * rsin[idx >> 6];
  }
  __syncthreads();
  const int o = o0 + (tid >> 2), dq = (tid & 3) * 16;
  const float* wrow = Wout + (size_t)o * CD + h * 64;
  float a[16] = {};
  for (int e2 = 0; e2 < 64; ++e2) {
    const float wv = wrow[e2];
#pragma unroll
    for (int i = 0; i < 16; ++i) a[i] += wv * cn[dq + i][e2];
  }
  u16x8 p0, p1;
#pragma unroll
  for (int i = 0; i < 8; ++i) { p0[i] = f2bf(a[i]); p1[i] = f2bf(a[8 + i]); }
  u16* dst = Weff + ((size_t)(b * CD + o)) * CD + h * 64 + dq;
  *(u16x8*)dst = p0;
  *(u16x8*)(dst + 8) = p1;
}

// ---------------- K3: final[b][o][t] = Weff[b] @ qhT + b_out ----------------
// 1024 blocks = 8 XCD x 128.
__global__ __launch_bounds__(512, 2) void k_final(const u16* __restrict__ Weff, const u16* __restrict__ qhT,
                                                  const float* __restrict__ bias, float* __restrict__ out) {
  __shared__ __align__(16) char LDS[147456];
  const int lid = blockIdx.x;
  const int wg = (lid & 7) * 128 + (lid >> 3);
  const int b = wg >> 7, r = wg & 127;
  const int mt = r & 1, nt = r >> 1;
  const int row0 = mt * 256, t0 = nt * 128;
  const int tid = threadIdx.x, lane = tid & 63, w = tid >> 6;
  const int wr = w >> 1, wc = w & 1, lo16 = lane & 15, hi4 = lane >> 4;
  const u16* Aw = Weff + ((size_t)(b * CD + row0 + w * 32)) * CD;
  f32x4 acc[4][4] = {};
  gemm256(Aw, qhT + ((size_t)b * TDIM + t0) * CD, LDS, acc);
#pragma unroll
  for (int am = 0; am < 4; ++am)
#pragma unroll
    for (int r2 = 0; r2 < 4; ++r2) {
      const int o = row0 + wr * 64 + am * 16 + hi4 * 4 + r2;
      const float bo = bias[o];
      float* orow = out + ((size_t)(b * CD + o)) * TDIM + t0 + wc * 64 + lo16;
#pragma unroll
      for (int an = 0; an < 4; ++an)
        orow[an * 16] = acc[am][an][r2] + bo;
    }
}

extern "C" void kernel_launch(void* const* d_in, const int* in_sizes, int n_in,
                              void* d_out, int out_size, void* d_ws, size_t ws_size,
                              hipStream_t stream) {
  const float* q    = (const float*)d_in[0];
  const float* Wq   = (const float*)d_in[1];
  const float* Wkv  = (const float*)d_in[2];
  const float* Wout = (const float*)d_in[3];
  const float* bout = (const float*)d_in[4];
  float* out = (float*)d_out;
  char* ws = (char*)d_ws;
  const size_t SZ = (size_t)NB * CD * TDIM * 2;   // 64 MiB per bf16 [8][512][8192] buffer
  u16* qT  = (u16*)ws;
  u16* qhT = (u16*)(ws + SZ);
  char* base = ws + 2 * SZ;
  u16* Wall   = (u16*)base;                       // 1.5 MB
  float* ctx  = (float*)(base + (2u << 20));      // 1 MB
  float* rsum = (float*)(base + (3u << 20));      // 16 KB
  u16* Weff   = (u16*)(base + (4u << 20));        // 4 MB
  (void)in_sizes; (void)n_in; (void)out_size; (void)ws_size;

  hipMemsetAsync(base + (2u << 20), 0, 2u << 20, stream);  // zero ctx + rowsum accumulators
  k_tq    <<<dim3(128, 8, 8), 256, 0, stream>>>(q, qT);
  k_cast_w<<<dim3(768), 256, 0, stream>>>(Wq, Wkv, Wall);
  k_proj  <<<dim3(3072), 512, 0, stream>>>(Wall, qT, qhT, ctx, rsum);
  k_weff  <<<dim3(8, 64), 256, 0, stream>>>(Wout, ctx, rsum, Weff);
  k_final <<<dim3(1024), 512, 0, stream>>>(Weff, qhT, bout, out);
}